// Round 4
// baseline (1461.290 us; speedup 1.0000x reference)
//
#include <hip/hip_runtime.h>

// RecyclingEmbedder: out[i][j][p] = b[p] + (bin(d_ij) fired ? W[p][bin] : 0)
// Output = 16-row table lookup -> pure write-BW problem (1.208 GB fp32).
//
// History:
//  R2(s1): nontemporal stores ~1.0 TB/s -> plain stores.
//  R1: occupancy 24->32 waves/CU: null -> not latency-bound.
//  R3: flat fill-pattern linear sweep: null (1205us) -> row-thrash theory DEAD.
//  All 3 structures ~= 1160-1205us. Kernel's own counters never observed
//  (every top-5 row is the harness 4.83GB poison fill).
//
// R4 = DIAGNOSTIC ROUND: identical R3 structure, but stream_kernel makes TWO
// idempotent passes over the output (second pass rewrites identical values;
// asm memory barrier prevents dead-store elimination). Purpose:
//  (a) stream dispatch grows to ~800+us -> enters rocprof top-5 -> first
//      direct read of FETCH_SIZE/WRITE_SIZE/hbm_gbps for OUR stores.
//      FETCH~=WRITE~=2.4GB => write-allocate/RFO. FETCH~=0 => true write cap.
//  (b) per-pass time = dur_us - 1205 (R3 baseline), separating kernel time
//      from the suspected in-graph fill (~770us).
// NEXT ROUND: revert to single pass and apply whichever fix the counters pick.

#define NBINS 15
#define NPTS  1536
#define DPAIR 128
#define NPAIR (NPTS * NPTS)                  // 2359296 pairs
#define TOT_F4 (NPAIR * (DPAIR / 4))         // 75497472 output float4
#define SBLOCKS 2048
#define NT (SBLOCKS * 256)                   // 524288 threads
#define NITER (TOT_F4 / NT)                  // 144, exact (no tail)

#define TAB_BYTES (16 * DPAIR * 4)           // 8192
#define WS_NEEDED (TAB_BYTES + NPAIR)        // 8 KB + 2.36 MB

typedef float f32x4 __attribute__((ext_vector_type(4)));

// ---------------- dispatch 1: prep (idx table + expanded row table) ---------
__global__ __launch_bounds__(256) void prep_kernel(
    const float* __restrict__ x,   // [NPTS,3]
    const float* __restrict__ W,   // [DPAIR,NBINS] row-major
    const float* __restrict__ b,   // [DPAIR]
    float* __restrict__ tab,       // [16*DPAIR] in ws
    unsigned char* __restrict__ idx) {  // [NPAIR] in ws
    const int i = blockIdx.x;
    const int t = threadIdx.x;

    // squared bin edges: exact multiples of 0.25 -> exact fp32; squaring
    // rounds identically to numpy's **2 in float32.
    float bins[NBINS];
#pragma unroll
    for (int k = 0; k < NBINS; ++k) {
        float e = 3.25f + 1.25f * (float)k;
        bins[k] = e * e;
    }

    // Block 0 additionally builds the 16-row table (row 0 = b, row k = b+W[:,k-1]).
    if (i == 0) {
        for (int e = t; e < 16 * DPAIR; e += 256) {
            int row = e >> 7;            // 0..15
            int p   = e & (DPAIR - 1);
            float v = b[p];
            if (row > 0) v += W[p * NBINS + (row - 1)];
            tab[e] = v;
        }
    }

    const float xi0 = x[i * 3 + 0];
    const float xi1 = x[i * 3 + 1];
    const float xi2 = x[i * 3 + 2];
    for (int j = t; j < NPTS; j += 256) {
        float d;
        {
            // Bit-exact vs numpy: individually-rounded squares, left-to-right
            // sum, no fma contraction.
#pragma clang fp contract(off)
            float dx = xi0 - x[j * 3 + 0];
            float dy = xi1 - x[j * 3 + 1];
            float dz = xi2 - x[j * 3 + 2];
            d = dx * dx + dy * dy + dz * dz;
        }
        int cnt = 0, eq = 0;
#pragma unroll
        for (int k = 0; k < NBINS; ++k) {
            cnt += (d > bins[k]) ? 1 : 0;
            eq  |= (d == bins[k]) ? 1 : 0;
        }
        // exact edge hit -> one-hot all zero -> row 0 (b only)
        idx[i * NPTS + j] = (unsigned char)(eq ? 0 : cnt);
    }
}

// ------- dispatch 2: linear-sweep writer, TWO idempotent passes (diag) ------
__global__ __launch_bounds__(256, 8) void stream_kernel(
    const float* __restrict__ tab,           // [16*DPAIR] in ws
    const unsigned char* __restrict__ idx,   // [NPAIR] in ws
    float* __restrict__ out) {               // [NPTS,NPTS,DPAIR]
    const f32x4* tab4 = (const f32x4*)tab;
    f32x4* out4 = (f32x4*)out;

    const unsigned flat = blockIdx.x * 256u + threadIdx.x;
    const unsigned w = flat & 31u;           // thread-constant f4 lane in feature row

    for (int pass = 0; pass < 2; ++pass) {
        // Whole GPU sweeps one contiguous 8 MB window per iteration.
#pragma unroll 4
        for (int it = 0; it < NITER; ++it) {
            unsigned g = flat + (unsigned)it * (unsigned)NT;  // global f4 index
            unsigned p = g >> 5;                 // pair index (i*NPTS+j)
            unsigned id = idx[p];                // 32-lane broadcast, L2-resident
            out4[g] = tab4[id * 32u + w];        // 16B from L1-resident 8KB table
        }
        // Compiler-level memory barrier: pass-1 stores may not be proven dead
        // against pass-2's identical stores. Zero instructions emitted.
        asm volatile("" ::: "memory");
    }
}

// ---------------- fallback (R1 kernel) if ws is too small -------------------
#define JSPLIT 2
#define JCHUNK (NPTS / JSPLIT)
#define CHUNK_F4 (JCHUNK * DPAIR / 4)

__global__ __launch_bounds__(256, 8) void recycling_embedder_fallback(
    const float* __restrict__ x,
    const float* __restrict__ W,
    const float* __restrict__ b,
    float* __restrict__ out) {
    __shared__ float table[16 * DPAIR];
    __shared__ unsigned short offs[JCHUNK];

    const int i    = blockIdx.x >> 1;
    const int half = blockIdx.x & 1;
    const int t    = threadIdx.x;

    float bins[NBINS];
#pragma unroll
    for (int k = 0; k < NBINS; ++k) {
        float e = 3.25f + 1.25f * (float)k;
        bins[k] = e * e;
    }

    for (int e = t; e < 16 * DPAIR; e += 256) {
        int row = e >> 7;
        int p   = e & (DPAIR - 1);
        float v = b[p];
        if (row > 0) v += W[p * NBINS + (row - 1)];
        table[e] = v;
    }

    const float xi0 = x[i * 3 + 0];
    const float xi1 = x[i * 3 + 1];
    const float xi2 = x[i * 3 + 2];
    const int j0 = half * JCHUNK;
    for (int jj = t; jj < JCHUNK; jj += 256) {
        int j = j0 + jj;
        float d;
        {
#pragma clang fp contract(off)
            float dx = xi0 - x[j * 3 + 0];
            float dy = xi1 - x[j * 3 + 1];
            float dz = xi2 - x[j * 3 + 2];
            d = dx * dx + dy * dy + dz * dz;
        }
        int cnt = 0, eq = 0;
#pragma unroll
        for (int k = 0; k < NBINS; ++k) {
            cnt += (d > bins[k]) ? 1 : 0;
            eq  |= (d == bins[k]) ? 1 : 0;
        }
        int bidx = eq ? 0 : cnt;
        offs[jj] = (unsigned short)(bidx * (DPAIR / 4));
    }
    __syncthreads();

    const f32x4* table4 = (const f32x4*)table;
    f32x4* ochunk = (f32x4*)out
                  + (size_t)i * (NPTS * DPAIR / 4)
                  + (size_t)(j0 * (DPAIR / 4));
#pragma unroll 4
    for (int l = t; l < CHUNK_F4; l += 256) {
        int jj     = l >> 5;
        int within = l & 31;
        ochunk[l] = table4[offs[jj] + within];
    }
}

extern "C" void kernel_launch(void* const* d_in, const int* in_sizes, int n_in,
                              void* d_out, int out_size, void* d_ws, size_t ws_size,
                              hipStream_t stream) {
    const float* x = (const float*)d_in[0];
    const float* W = (const float*)d_in[1];
    const float* b = (const float*)d_in[2];
    float* out = (float*)d_out;

    if (ws_size >= (size_t)WS_NEEDED && d_ws != nullptr) {
        float* tab = (float*)d_ws;
        unsigned char* idx = (unsigned char*)d_ws + TAB_BYTES;

        // Dispatch 1: per-pair bin index + expanded table (~15 us).
        prep_kernel<<<dim3(NPTS), dim3(256), 0, stream>>>(x, W, b, tab, idx);
        // Dispatch 2: linear-sweep writer, TWO idempotent passes (diagnostic:
        // makes the dispatch long enough to surface in rocprof top-5).
        stream_kernel<<<dim3(SBLOCKS), dim3(256), 0, stream>>>(tab, idx, out);
    } else {
        recycling_embedder_fallback<<<dim3(NPTS * JSPLIT), dim3(256), 0, stream>>>(
            x, W, b, out);
    }
}

// Round 5
// 1170.574 us; speedup vs baseline: 1.2484x; 1.2484x over previous
//
#include <hip/hip_runtime.h>

// RecyclingEmbedder: out[i][j][p] = b[p] + (bin(d_ij) fired ? W[p][bin] : 0)
// Output = 16-row table lookup -> pure write-BW problem (1.208 GB fp32).
//
// History:
//  R2(s1): nontemporal stores ~1.0 TB/s -> plain stores.
//  R1: occupancy 24->32 waves/CU: null -> not latency-bound at unroll-4... or so we thought.
//  R3: flat fill-pattern linear sweep (2 dispatch): 1205us -> row-thrash theory DEAD.
//  R4 DIAG: double idempotent pass: dur 1205->1461 => MARGINAL full-output sweep
//    = 256us = 4.72 TB/s, while every single-pass structure sits at ~400us
//    (~3.0 TB/s). Store stream CAN do 4.7; single pass doesn't.
//  Surviving theory: 2-level LDS dependency chain (u16 offs -> b128 table ->
//    store), ~240cyc/iter, unroll-4 under the 64-VGPR lb(256,8) cap gives
//    ~6 waves x 4 iters in flight -> ~3.9 TB/s predicted ~= observed plateau.
//
// R5: break the chain.
//  - offs stored COLUMN-major: thread's jj sequence is t/32 + it*8, so one
//    ds_read_b128 fetches 8 iterations of offsets (13 LDS reads + 8 stores
//    per 128 B/thread, was 16+8).
//  - explicit 2-group software pipeline (fully unrolled, static reg indices),
//    group g's 8 stores issue while group g+1's loads are in flight.
//  - lb(256,4): ~90 VGPR for double-buffered f32x4[8] x2; 16 waves/CU
//    (occupancy shown insensitive in R1; ILP replaces TLP).
//  - single fused dispatch, no workspace.

#define NBINS 15
#define NPTS  1536
#define DPAIR 128
#define JSPLIT 2
#define JCHUNK (NPTS / JSPLIT)          // 768 pairs per block
#define CHUNK_F4 (JCHUNK * DPAIR / 4)   // 24576 float4 per block
#define NGROUP 12                       // 12 groups x 8 iters x 256 thr = 24576

typedef float f32x4 __attribute__((ext_vector_type(4)));
typedef unsigned short u16x8 __attribute__((ext_vector_type(8)));

__global__ __launch_bounds__(256, 4) void recycling_embedder_kernel(
    const float* __restrict__ x,   // [NPTS,3]
    const float* __restrict__ W,   // [DPAIR,NBINS] row-major
    const float* __restrict__ b,   // [DPAIR]
    float* __restrict__ out) {     // [NPTS,NPTS,DPAIR]
    __shared__ __align__(16) float table[16 * DPAIR];        // 8 KB
    // Column-major offset table: offsC[t32*96 + it] = byte row-offset for
    // pair jj = t32 + it*8.  Thread (t) reads offsC[(t>>5)*96 + it], so a
    // group of 8 consecutive its is one aligned 16B ds_read_b128.
    __shared__ __align__(16) unsigned short offsC[8 * 96];   // 1.5 KB

    const int i    = blockIdx.x >> 1;   // output row
    const int half = blockIdx.x & 1;    // which j-half of the row
    const int t    = threadIdx.x;

    // squared bin edges: exact multiples of 0.25 -> exact fp32; squaring
    // rounds identically to numpy's **2 in float32.
    float bins[NBINS];
#pragma unroll
    for (int k = 0; k < NBINS; ++k) {
        float e = 3.25f + 1.25f * (float)k;
        bins[k] = e * e;
    }

    // Build the 16-row lookup table (row 0 = b only; row k = b + W[:,k-1]).
    for (int e = t; e < 16 * DPAIR; e += 256) {
        int row = e >> 7;            // 0..15
        int p   = e & (DPAIR - 1);
        float v = b[p];
        if (row > 0) v += W[p * NBINS + (row - 1)];
        table[e] = v;
    }

    // Per-j bin index -> column-major byte offsets.
    const float xi0 = x[i * 3 + 0];
    const float xi1 = x[i * 3 + 1];
    const float xi2 = x[i * 3 + 2];
    const int j0 = half * JCHUNK;
    for (int jj = t; jj < JCHUNK; jj += 256) {
        int j = j0 + jj;
        float d;
        {
            // Bit-exact vs numpy: individually-rounded squares, left-to-right
            // sum, no fma contraction.
#pragma clang fp contract(off)
            float dx = xi0 - x[j * 3 + 0];
            float dy = xi1 - x[j * 3 + 1];
            float dz = xi2 - x[j * 3 + 2];
            d = dx * dx + dy * dy + dz * dz;
        }
        int cnt = 0, eq = 0;
#pragma unroll
        for (int k = 0; k < NBINS; ++k) {
            cnt += (d > bins[k]) ? 1 : 0;
            eq  |= (d == bins[k]) ? 1 : 0;
        }
        // exact edge hit -> one-hot all zero -> row 0 (b only)
        int idx = eq ? 0 : cnt;
        offsC[(jj & 7) * 96 + (jj >> 3)] = (unsigned short)(idx * (DPAIR * 4)); // idx*512B
    }
    __syncthreads();

    // ---- streaming phase: software-pipelined, 12 groups of 8 f32x4/thread ----
    const char* tabc = (const char*)table;
    const char* offc = (const char*)offsC + (t >> 5) * 192;  // this thread's column
    const int   wb   = (t & 31) * 16;    // thread-constant byte offset in table row

    f32x4* ochunk = (f32x4*)out
                  + (size_t)i * (NPTS * DPAIR / 4)
                  + (size_t)(j0 * (DPAIR / 4));

    u16x8 offA, offB;
    f32x4 valA[8], valB[8];

#define FETCH_OFF(g, o) (o) = *(const u16x8*)(offc + (g) * 16)
#define FETCH_VAL(o, v)                                            \
    _Pragma("unroll")                                              \
    for (int u = 0; u < 8; ++u)                                    \
        (v)[u] = *(const f32x4*)(tabc + (o)[u] + wb)
#define STORE_G(g, v)                                              \
    _Pragma("unroll")                                              \
    for (int u = 0; u < 8; ++u)                                    \
        ochunk[((g) * 8 + u) * 256 + t] = (v)[u]

    // Prologue: fill buffer A.
    FETCH_OFF(0, offA);
    FETCH_VAL(offA, valA);

#pragma unroll
    for (int g = 0; g < NGROUP; g += 2) {
        if (g + 1 < NGROUP) { FETCH_OFF(g + 1, offB); FETCH_VAL(offB, valB); }
        STORE_G(g, valA);                 // 8x 1KiB wave-stores, data ready
        if (g + 2 < NGROUP) { FETCH_OFF(g + 2, offA); FETCH_VAL(offA, valA); }
        if (g + 1 < NGROUP) STORE_G(g + 1, valB);
    }

#undef FETCH_OFF
#undef FETCH_VAL
#undef STORE_G
}

extern "C" void kernel_launch(void* const* d_in, const int* in_sizes, int n_in,
                              void* d_out, int out_size, void* d_ws, size_t ws_size,
                              hipStream_t stream) {
    const float* x = (const float*)d_in[0];
    const float* W = (const float*)d_in[1];
    const float* b = (const float*)d_in[2];
    float* out = (float*)d_out;

    // 2 blocks per output row i: 3072 blocks, 4 resident/CU (lb(256,4)),
    // 16 waves/CU; deep ILP via the explicit 2-group pipeline.
    dim3 grid(NPTS * JSPLIT), block(256);
    recycling_embedder_kernel<<<grid, block, 0, stream>>>(x, W, b, out);
}